// Round 2
// baseline (390.740 us; speedup 1.0000x reference)
//
#include <hip/hip_runtime.h>
#include <hip/hip_bf16.h>

#define B_  32
#define C_  1024
#define N_  256
#define DQ_ 64

typedef __bf16 bf16_t;
typedef __bf16 bf16x8 __attribute__((ext_vector_type(8)));
typedef float  f32x4  __attribute__((ext_vector_type(4)));

static __device__ __forceinline__ f32x4 mfma16(bf16x8 a, bf16x8 b, f32x4 c) {
  return __builtin_amdgcn_mfma_f32_16x16x32_bf16(a, b, c, 0, 0, 0);
}

// two contiguous float4 -> bf16x8 (RNE via HW cvt)
static __device__ __forceinline__ bf16x8 cvt8(const float4 a, const float4 b) {
  bf16x8 r;
  r[0] = (bf16_t)a.x; r[1] = (bf16_t)a.y; r[2] = (bf16_t)a.z; r[3] = (bf16_t)a.w;
  r[4] = (bf16_t)b.x; r[5] = (bf16_t)b.y; r[6] = (bf16_t)b.z; r[7] = (bf16_t)b.w;
  return r;
}

static __device__ __forceinline__ bf16x8 ldcvt(const float* p) {
  const float4 a = *(const float4*)p;
  const float4 b = *(const float4*)(p + 4);
  return cvt8(a, b);
}

// ---------------- Kernel 1: q/k projection ----------------
// qt[b][c][o] = relu(bn(dot(W[o,:], x[b,c,:])))   (position-major store)
__global__ __launch_bounds__(256) void k_proj(const float* __restrict__ x,
                                              const float* __restrict__ W,
                                              const float* __restrict__ g,
                                              const float* __restrict__ be,
                                              const float* __restrict__ mu,
                                              const float* __restrict__ va,
                                              bf16_t* __restrict__ outT) {
  const int tid  = threadIdx.x;
  const int wave = tid >> 6;
  const int lane = tid & 63;
  const int quad = lane >> 4;
  const int l16  = lane & 15;
  const int b    = blockIdx.y;
  const int cbase = blockIdx.x * 256 + wave * 64;
  const float* xb = x + (size_t)b * C_ * N_;

  f32x4 acc[4][4];
#pragma unroll
  for (int i = 0; i < 4; ++i)
#pragma unroll
    for (int j = 0; j < 4; ++j)
      acc[i][j] = (f32x4){0.f, 0.f, 0.f, 0.f};

  for (int ks = 0; ks < 8; ++ks) {
    const int k0 = ks * 32 + quad * 8;
    bf16x8 a[4], bb[4];
#pragma unroll
    for (int i = 0; i < 4; ++i)
      a[i] = ldcvt(W + (size_t)(i * 16 + l16) * N_ + k0);
#pragma unroll
    for (int j = 0; j < 4; ++j)
      bb[j] = ldcvt(xb + (size_t)(cbase + j * 16 + l16) * N_ + k0);
#pragma unroll
    for (int i = 0; i < 4; ++i)
#pragma unroll
      for (int j = 0; j < 4; ++j)
        acc[i][j] = mfma16(a[i], bb[j], acc[i][j]);
  }

#pragma unroll
  for (int i = 0; i < 4; ++i)
#pragma unroll
    for (int r = 0; r < 4; ++r) {
      const int o = i * 16 + quad * 4 + r;
      const float sc = g[o] * rsqrtf(va[o] + 1e-5f);
      const float mm = mu[o], bt = be[o];
#pragma unroll
      for (int j = 0; j < 4; ++j) {
        const int c = cbase + j * 16 + l16;
        float y = (acc[i][j][r] - mm) * sc + bt;
        y = fmaxf(y, 0.f);
        outT[((size_t)b * C_ + c) * DQ_ + o] = (bf16_t)y;
      }
    }
}

// ---------------- Kernel 2: v GEMM (transpose fused via LDS) ----------------
// vT[b][n][o] = relu(bn3( sum_c Wv[o][c] * x[b][c][n] ))
__global__ __launch_bounds__(256) void k_vgemm(const float* __restrict__ Wv,
                                               const float* __restrict__ x,
                                               const float* __restrict__ g,
                                               const float* __restrict__ be,
                                               const float* __restrict__ mu,
                                               const float* __restrict__ va,
                                               bf16_t* __restrict__ vT) {
  __shared__ __align__(16) bf16_t xs[128][40];  // [n_local][c_local], pad 32->40
  const int tid  = threadIdx.x;
  const int wave = tid >> 6;
  const int lane = tid & 63;
  const int quad = lane >> 4;
  const int l16  = lane & 15;
  const int b      = blockIdx.z;
  const int m0     = blockIdx.x * 128 + (wave >> 1) * 64;   // o-tile
  const int n0_blk = blockIdx.y * 128;                      // block n-tile
  const int nw     = (wave & 1) * 64;                       // wave n-offset
  const float* xb = x + (size_t)b * C_ * N_;

  f32x4 acc[4][4];
#pragma unroll
  for (int i = 0; i < 4; ++i)
#pragma unroll
    for (int j = 0; j < 4; ++j)
      acc[i][j] = (f32x4){0.f, 0.f, 0.f, 0.f};

  const int c_l = tid >> 3;          // 0..31
  const int nb  = (tid & 7) * 16;    // 0..112

  for (int c0 = 0; c0 < C_; c0 += 32) {
    __syncthreads();
    // stage x[b][c0..c0+31][n0_blk..n0_blk+127] -> xs transposed, cvt to bf16
    {
      const float* src = xb + (size_t)(c0 + c_l) * N_ + n0_blk + nb;
      const float4 f0 = *(const float4*)(src);
      const float4 f1 = *(const float4*)(src + 4);
      const float4 f2 = *(const float4*)(src + 8);
      const float4 f3 = *(const float4*)(src + 12);
      xs[nb +  0][c_l] = (bf16_t)f0.x; xs[nb +  1][c_l] = (bf16_t)f0.y;
      xs[nb +  2][c_l] = (bf16_t)f0.z; xs[nb +  3][c_l] = (bf16_t)f0.w;
      xs[nb +  4][c_l] = (bf16_t)f1.x; xs[nb +  5][c_l] = (bf16_t)f1.y;
      xs[nb +  6][c_l] = (bf16_t)f1.z; xs[nb +  7][c_l] = (bf16_t)f1.w;
      xs[nb +  8][c_l] = (bf16_t)f2.x; xs[nb +  9][c_l] = (bf16_t)f2.y;
      xs[nb + 10][c_l] = (bf16_t)f2.z; xs[nb + 11][c_l] = (bf16_t)f2.w;
      xs[nb + 12][c_l] = (bf16_t)f3.x; xs[nb + 13][c_l] = (bf16_t)f3.y;
      xs[nb + 14][c_l] = (bf16_t)f3.z; xs[nb + 15][c_l] = (bf16_t)f3.w;
    }
    __syncthreads();

    bf16x8 a[4], bb[4];
#pragma unroll
    for (int i = 0; i < 4; ++i)
      a[i] = ldcvt(Wv + (size_t)(m0 + i * 16 + l16) * C_ + c0 + quad * 8);
#pragma unroll
    for (int j = 0; j < 4; ++j)
      bb[j] = *(const bf16x8*)(&xs[nw + j * 16 + l16][quad * 8]);
#pragma unroll
    for (int i = 0; i < 4; ++i)
#pragma unroll
      for (int j = 0; j < 4; ++j)
        acc[i][j] = mfma16(a[i], bb[j], acc[i][j]);
  }

#pragma unroll
  for (int i = 0; i < 4; ++i)
#pragma unroll
    for (int r = 0; r < 4; ++r) {
      const int o = m0 + i * 16 + quad * 4 + r;
      const float sc = g[o] * rsqrtf(va[o] + 1e-5f);
      const float mm = mu[o], bt = be[o];
#pragma unroll
      for (int j = 0; j < 4; ++j) {
        const int n = n0_blk + nw + j * 16 + l16;
        float y = (acc[i][j][r] - mm) * sc + bt;
        y = fmaxf(y, 0.f);
        vT[((size_t)b * N_ + n) * C_ + o] = (bf16_t)y;
      }
    }
}

// ---------------- Kernel 3: fused sim -> softmax -> out ----------------
__global__ __launch_bounds__(256) void k_fused(const bf16_t* __restrict__ qt,
                                               const bf16_t* __restrict__ kt,
                                               const bf16_t* __restrict__ vT,
                                               const float* __restrict__ x,
                                               const float* __restrict__ alphap,
                                               float* __restrict__ out) {
  __shared__ __align__(16) bf16_t ebuf[16][1032];
  __shared__ float redmin[4][16];
  __shared__ float redsum[4][16];
  __shared__ float rowmin[16];
  __shared__ float rowrinv[16];

  const int tid  = threadIdx.x;
  const int wave = tid >> 6;
  const int lane = tid & 63;
  const int quad = lane >> 4;
  const int l16  = lane & 15;
  const int b    = blockIdx.y;
  const int c0   = blockIdx.x * 16;
  const int dbase = wave * 256;

  // Phase A: sim (16 c-rows x this wave's 256 d-cols, K=64)
  const bf16_t* ktb = kt + ((size_t)b * C_ + c0) * DQ_;
  const bf16_t* qb  = qt + (size_t)b * C_ * DQ_;
  const bf16x8 a0 = *(const bf16x8*)(ktb + l16 * DQ_ + quad * 8);
  const bf16x8 a1 = *(const bf16x8*)(ktb + l16 * DQ_ + 32 + quad * 8);
  f32x4 sim[16];
#pragma unroll
  for (int nt = 0; nt < 16; ++nt) {
    const bf16_t* qrow = qb + (size_t)(dbase + nt * 16 + l16) * DQ_ + quad * 8;
    const bf16x8 b0 = *(const bf16x8*)(qrow);
    const bf16x8 b1 = *(const bf16x8*)(qrow + 32);
    f32x4 acc = (f32x4){0.f, 0.f, 0.f, 0.f};
    acc = mfma16(a0, b0, acc);
    acc = mfma16(a1, b1, acc);
    sim[nt] = acc;
  }

  // Phase B: row-min shift, exp, row-sum.  softmax(M - sim) == exp(min - sim)/S
  float pmin[4];
#pragma unroll
  for (int r = 0; r < 4; ++r) pmin[r] = sim[0][r];
#pragma unroll
  for (int nt = 1; nt < 16; ++nt)
#pragma unroll
    for (int r = 0; r < 4; ++r) pmin[r] = fminf(pmin[r], sim[nt][r]);
#pragma unroll
  for (int m = 1; m < 16; m <<= 1)
#pragma unroll
    for (int r = 0; r < 4; ++r) pmin[r] = fminf(pmin[r], __shfl_xor(pmin[r], m));
  if (l16 == 0)
#pragma unroll
    for (int r = 0; r < 4; ++r) redmin[wave][quad * 4 + r] = pmin[r];
  __syncthreads();
  if (tid < 16)
    rowmin[tid] = fminf(fminf(redmin[0][tid], redmin[1][tid]),
                        fminf(redmin[2][tid], redmin[3][tid]));
  __syncthreads();

  float mn[4], psum[4] = {0.f, 0.f, 0.f, 0.f};
#pragma unroll
  for (int r = 0; r < 4; ++r) mn[r] = rowmin[quad * 4 + r];
#pragma unroll
  for (int nt = 0; nt < 16; ++nt)
#pragma unroll
    for (int r = 0; r < 4; ++r) {
      const float e = __expf(mn[r] - sim[nt][r]);
      ebuf[quad * 4 + r][dbase + nt * 16 + l16] = (bf16_t)e;
      psum[r] += e;
    }
#pragma unroll
  for (int m = 1; m < 16; m <<= 1)
#pragma unroll
    for (int r = 0; r < 4; ++r) psum[r] += __shfl_xor(psum[r], m);
  if (l16 == 0)
#pragma unroll
    for (int r = 0; r < 4; ++r) redsum[wave][quad * 4 + r] = psum[r];
  __syncthreads();
  if (tid < 16)
    rowrinv[tid] = 1.f / (redsum[0][tid] + redsum[1][tid] + redsum[2][tid] + redsum[3][tid]);
  __syncthreads();

  // Phase C: out[c][n2] = sum_d e[c][d] * vT[b][n2][d]; wave owns 64 n2-cols, K=1024.
  const bf16_t* vb = vT + (size_t)b * N_ * C_;
  const int n2b = wave * 64;
  f32x4 oacc[4];
#pragma unroll
  for (int j = 0; j < 4; ++j) oacc[j] = (f32x4){0.f, 0.f, 0.f, 0.f};
  for (int ks = 0; ks < 32; ++ks) {
    const int k0 = ks * 32 + quad * 8;
    const bf16x8 af = *(const bf16x8*)(&ebuf[l16][k0]);
#pragma unroll
    for (int j = 0; j < 4; ++j) {
      const bf16x8 bf = *(const bf16x8*)(vb + (size_t)(n2b + j * 16 + l16) * C_ + k0);
      oacc[j] = mfma16(af, bf, oacc[j]);
    }
  }

  const float alpha = alphap[0];
#pragma unroll
  for (int j = 0; j < 4; ++j)
#pragma unroll
    for (int r = 0; r < 4; ++r) {
      const int c = c0 + quad * 4 + r;
      const int n = n2b + j * 16 + l16;
      const size_t idx = ((size_t)b * C_ + c) * N_ + n;
      out[idx] = alpha * (oacc[j][r] * rowrinv[quad * 4 + r]) + x[idx];
    }
}

extern "C" void kernel_launch(void* const* d_in, const int* in_sizes, int n_in,
                              void* d_out, int out_size, void* d_ws, size_t ws_size,
                              hipStream_t stream) {
  const float* x    = (const float*)d_in[0];
  const float* Wq   = (const float*)d_in[1];
  const float* Wk   = (const float*)d_in[2];
  const float* Wv   = (const float*)d_in[3];
  const float* bn1g = (const float*)d_in[4];
  const float* bn1b = (const float*)d_in[5];
  const float* bn1m = (const float*)d_in[6];
  const float* bn1v = (const float*)d_in[7];
  const float* bn2g = (const float*)d_in[8];
  const float* bn2b = (const float*)d_in[9];
  const float* bn2m = (const float*)d_in[10];
  const float* bn2v = (const float*)d_in[11];
  const float* bn3g = (const float*)d_in[12];
  const float* bn3b = (const float*)d_in[13];
  const float* bn3m = (const float*)d_in[14];
  const float* bn3v = (const float*)d_in[15];
  const float* alph = (const float*)d_in[16];
  float* outp = (float*)d_out;

  char* ws = (char*)d_ws;
  bf16_t* qt = (bf16_t*)(ws);                          // 4 MiB  (B,C,DQ)
  bf16_t* kt = (bf16_t*)(ws + (size_t)4194304);        // 4 MiB  (B,C,DQ)
  bf16_t* vT = (bf16_t*)(ws + (size_t)8388608);        // 16 MiB (B,N,C)

  k_proj<<<dim3(4, 32), 256, 0, stream>>>(x, Wq, bn1g, bn1b, bn1m, bn1v, qt);
  k_proj<<<dim3(4, 32), 256, 0, stream>>>(x, Wk, bn2g, bn2b, bn2m, bn2v, kt);
  k_vgemm<<<dim3(8, 2, 32), 256, 0, stream>>>(Wv, x, bn3g, bn3b, bn3m, bn3v, vT);
  k_fused<<<dim3(64, 32), 256, 0, stream>>>(qt, kt, vT, x, alph, outp);
}

// Round 3
// 296.983 us; speedup vs baseline: 1.3157x; 1.3157x over previous
//
#include <hip/hip_runtime.h>
#include <hip/hip_bf16.h>

#define B_  32
#define C_  1024
#define N_  256
#define DQ_ 64

typedef __bf16 bf16_t;
typedef __bf16 bf16x8 __attribute__((ext_vector_type(8)));
typedef float  f32x4  __attribute__((ext_vector_type(4)));

static __device__ __forceinline__ f32x4 mfma16(bf16x8 a, bf16x8 b, f32x4 c) {
  return __builtin_amdgcn_mfma_f32_16x16x32_bf16(a, b, c, 0, 0, 0);
}

static __device__ __forceinline__ bf16x8 ldcvt(const float* p) {
  const float4 a = *(const float4*)p;
  const float4 b = *(const float4*)(p + 4);
  bf16x8 r;
  r[0] = (bf16_t)a.x; r[1] = (bf16_t)a.y; r[2] = (bf16_t)a.z; r[3] = (bf16_t)a.w;
  r[4] = (bf16_t)b.x; r[5] = (bf16_t)b.y; r[6] = (bf16_t)b.z; r[7] = (bf16_t)b.w;
  return r;
}

// ---------------- Kernel T: x (B,C,N) f32 -> xT (B,N,C) bf16 ----------------
__global__ __launch_bounds__(256) void k_trans(const float* __restrict__ x,
                                               bf16_t* __restrict__ xT) {
  __shared__ bf16_t tile[32][34];
  const int b  = blockIdx.z;
  const int n0 = blockIdx.x * 32, c0 = blockIdx.y * 32;
  const int tx = threadIdx.x, ty = threadIdx.y;
  const float* xb = x + (size_t)b * C_ * N_;
  bf16_t*     xtb = xT + (size_t)b * N_ * C_;
#pragma unroll
  for (int i = 0; i < 4; ++i)
    tile[ty + i * 8][tx] = (bf16_t)xb[(size_t)(c0 + ty + i * 8) * N_ + (n0 + tx)];
  __syncthreads();
#pragma unroll
  for (int i = 0; i < 4; ++i)
    xtb[(size_t)(n0 + ty + i * 8) * C_ + (c0 + tx)] = tile[tx][ty + i * 8];
}

// ---------------- Kernel CVT: Wv f32 -> bf16 ----------------
__global__ __launch_bounds__(256) void k_cvt(const float* __restrict__ src,
                                             bf16_t* __restrict__ dst) {
  const int i = (blockIdx.x * 256 + threadIdx.x) * 8;
  const float4 a = *(const float4*)(src + i);
  const float4 b = *(const float4*)(src + i + 4);
  bf16x8 r;
  r[0] = (bf16_t)a.x; r[1] = (bf16_t)a.y; r[2] = (bf16_t)a.z; r[3] = (bf16_t)a.w;
  r[4] = (bf16_t)b.x; r[5] = (bf16_t)b.y; r[6] = (bf16_t)b.z; r[7] = (bf16_t)b.w;
  *(bf16x8*)(dst + i) = r;
}

// ---------------- Kernel 1: fused q+k projection (reads x once) ----------------
__global__ __launch_bounds__(256) void k_qk(const float* __restrict__ x,
                                            const float* __restrict__ Wq,
                                            const float* __restrict__ Wk,
                                            const float* __restrict__ g1,
                                            const float* __restrict__ b1,
                                            const float* __restrict__ m1,
                                            const float* __restrict__ v1,
                                            const float* __restrict__ g2,
                                            const float* __restrict__ b2,
                                            const float* __restrict__ m2,
                                            const float* __restrict__ v2,
                                            bf16_t* __restrict__ qt,
                                            bf16_t* __restrict__ kt) {
  const int tid  = threadIdx.x;
  const int wave = tid >> 6;
  const int lane = tid & 63;
  const int quad = lane >> 4;
  const int l16  = lane & 15;
  const int b    = blockIdx.y;
  const int cbase = blockIdx.x * 256 + wave * 64;
  const float* xb = x + (size_t)b * C_ * N_;

  f32x4 acc[8][4];
#pragma unroll
  for (int i = 0; i < 8; ++i)
#pragma unroll
    for (int j = 0; j < 4; ++j)
      acc[i][j] = (f32x4){0.f, 0.f, 0.f, 0.f};

  for (int ks = 0; ks < 8; ++ks) {
    const int k0 = ks * 32 + quad * 8;
    bf16x8 aw[8], bx[4];
#pragma unroll
    for (int i = 0; i < 4; ++i) {
      aw[i]     = ldcvt(Wq + (size_t)(i * 16 + l16) * N_ + k0);
      aw[4 + i] = ldcvt(Wk + (size_t)(i * 16 + l16) * N_ + k0);
    }
#pragma unroll
    for (int j = 0; j < 4; ++j)
      bx[j] = ldcvt(xb + (size_t)(cbase + j * 16 + l16) * N_ + k0);
#pragma unroll
    for (int i = 0; i < 8; ++i)
#pragma unroll
      for (int j = 0; j < 4; ++j)
        acc[i][j] = mfma16(aw[i], bx[j], acc[i][j]);
  }

#pragma unroll
  for (int i = 0; i < 8; ++i) {
    const bool isq = (i < 4);
#pragma unroll
    for (int r = 0; r < 4; ++r) {
      const int o = (i & 3) * 16 + quad * 4 + r;
      const float sc = (isq ? g1[o] : g2[o]) * rsqrtf((isq ? v1[o] : v2[o]) + 1e-5f);
      const float mm = isq ? m1[o] : m2[o];
      const float bt = isq ? b1[o] : b2[o];
      bf16_t* dst = isq ? qt : kt;
#pragma unroll
      for (int j = 0; j < 4; ++j) {
        const int c = cbase + j * 16 + l16;
        float y = (acc[i][j][r] - mm) * sc + bt;
        y = fmaxf(y, 0.f);
        dst[((size_t)b * C_ + c) * DQ_ + o] = (bf16_t)y;
      }
    }
  }
}

// ---------------- Kernel 2: v GEMM (pure bf16, both operands k-contiguous) ----------------
// vT[b][n][o] = relu(bn3( sum_c Wvb[o][c] * xT[b][n][c] ))
__global__ __launch_bounds__(256) void k_vgemm(const bf16_t* __restrict__ Wvb,
                                               const bf16_t* __restrict__ xT,
                                               const float* __restrict__ g,
                                               const float* __restrict__ be,
                                               const float* __restrict__ mu,
                                               const float* __restrict__ va,
                                               bf16_t* __restrict__ vT) {
  const int tid  = threadIdx.x;
  const int wave = tid >> 6;
  const int lane = tid & 63;
  const int quad = lane >> 4;
  const int l16  = lane & 15;
  const int b    = blockIdx.z;
  const int m0   = blockIdx.x * 128 + (wave >> 1) * 64;
  const int n0   = blockIdx.y * 128 + (wave & 1) * 64;
  const bf16_t* xb = xT + (size_t)b * N_ * C_;

  f32x4 acc[4][4];
#pragma unroll
  for (int i = 0; i < 4; ++i)
#pragma unroll
    for (int j = 0; j < 4; ++j)
      acc[i][j] = (f32x4){0.f, 0.f, 0.f, 0.f};

  for (int ks = 0; ks < 32; ++ks) {
    const int k0 = ks * 32 + quad * 8;
    bf16x8 a[4], bb[4];
#pragma unroll
    for (int i = 0; i < 4; ++i)
      a[i] = *(const bf16x8*)(Wvb + (size_t)(m0 + i * 16 + l16) * C_ + k0);
#pragma unroll
    for (int j = 0; j < 4; ++j)
      bb[j] = *(const bf16x8*)(xb + (size_t)(n0 + j * 16 + l16) * C_ + k0);
#pragma unroll
    for (int i = 0; i < 4; ++i)
#pragma unroll
      for (int j = 0; j < 4; ++j)
        acc[i][j] = mfma16(a[i], bb[j], acc[i][j]);
  }

#pragma unroll
  for (int i = 0; i < 4; ++i)
#pragma unroll
    for (int r = 0; r < 4; ++r) {
      const int o = m0 + i * 16 + quad * 4 + r;
      const float sc = g[o] * rsqrtf(va[o] + 1e-5f);
      const float mm = mu[o], bt = be[o];
#pragma unroll
      for (int j = 0; j < 4; ++j) {
        const int n = n0 + j * 16 + l16;
        float y = (acc[i][j][r] - mm) * sc + bt;
        y = fmaxf(y, 0.f);
        vT[((size_t)b * N_ + n) * C_ + o] = (bf16_t)y;
      }
    }
}

// ---------------- Kernel 3: fused sim -> softmax -> out  (32 c-rows / block) ----------------
__global__ __launch_bounds__(256, 2) void k_fused(const bf16_t* __restrict__ qt,
                                                  const bf16_t* __restrict__ kt,
                                                  const bf16_t* __restrict__ vT,
                                                  const float* __restrict__ x,
                                                  const float* __restrict__ alphap,
                                                  float* __restrict__ out) {
  __shared__ __align__(16) bf16_t ebuf[32][1032];
  __shared__ float redmin[4][32];
  __shared__ float redsum[4][32];
  __shared__ float rowmin[32];
  __shared__ float rowrinv[32];

  const int tid  = threadIdx.x;
  const int wave = tid >> 6;
  const int lane = tid & 63;
  const int quad = lane >> 4;
  const int l16  = lane & 15;
  const int b    = blockIdx.y;
  const int c0   = blockIdx.x * 32;
  const int dbase = wave * 256;

  // Phase A: sim (32 c-rows x this wave's 256 d-cols, K=64)
  const bf16_t* ktb = kt + ((size_t)b * C_ + c0) * DQ_;
  const bf16_t* qb  = qt + (size_t)b * C_ * DQ_;
  bf16x8 am[2][2];
#pragma unroll
  for (int i = 0; i < 2; ++i) {
    am[i][0] = *(const bf16x8*)(ktb + (size_t)(i * 16 + l16) * DQ_ + quad * 8);
    am[i][1] = *(const bf16x8*)(ktb + (size_t)(i * 16 + l16) * DQ_ + 32 + quad * 8);
  }
  f32x4 sim[2][16];
#pragma unroll
  for (int nt = 0; nt < 16; ++nt) {
    const bf16_t* qrow = qb + (size_t)(dbase + nt * 16 + l16) * DQ_ + quad * 8;
    const bf16x8 b0 = *(const bf16x8*)(qrow);
    const bf16x8 b1 = *(const bf16x8*)(qrow + 32);
#pragma unroll
    for (int i = 0; i < 2; ++i) {
      f32x4 acc = (i == 0) ? (f32x4){0.f, 0.f, 0.f, 0.f} : (f32x4){0.f, 0.f, 0.f, 0.f};
      acc = mfma16(am[i][0], b0, acc);
      acc = mfma16(am[i][1], b1, acc);
      sim[i][nt] = acc;
    }
  }

  // Phase B: row-min shift, exp, row-sum.  softmax(M - sim) == exp(min - sim)/S
  float pmin[2][4];
#pragma unroll
  for (int i = 0; i < 2; ++i)
#pragma unroll
    for (int r = 0; r < 4; ++r) pmin[i][r] = sim[i][0][r];
#pragma unroll
  for (int nt = 1; nt < 16; ++nt)
#pragma unroll
    for (int i = 0; i < 2; ++i)
#pragma unroll
      for (int r = 0; r < 4; ++r) pmin[i][r] = fminf(pmin[i][r], sim[i][nt][r]);
#pragma unroll
  for (int m = 1; m < 16; m <<= 1)
#pragma unroll
    for (int i = 0; i < 2; ++i)
#pragma unroll
      for (int r = 0; r < 4; ++r) pmin[i][r] = fminf(pmin[i][r], __shfl_xor(pmin[i][r], m));
  if (l16 == 0)
#pragma unroll
    for (int i = 0; i < 2; ++i)
#pragma unroll
      for (int r = 0; r < 4; ++r) redmin[wave][i * 16 + quad * 4 + r] = pmin[i][r];
  __syncthreads();
  if (tid < 32)
    rowmin[tid] = fminf(fminf(redmin[0][tid], redmin[1][tid]),
                        fminf(redmin[2][tid], redmin[3][tid]));
  __syncthreads();

  float mn[2][4], psum[2][4];
#pragma unroll
  for (int i = 0; i < 2; ++i)
#pragma unroll
    for (int r = 0; r < 4; ++r) {
      mn[i][r] = rowmin[i * 16 + quad * 4 + r];
      psum[i][r] = 0.f;
    }
#pragma unroll
  for (int nt = 0; nt < 16; ++nt)
#pragma unroll
    for (int i = 0; i < 2; ++i)
#pragma unroll
      for (int r = 0; r < 4; ++r) {
        const float e = __expf(mn[i][r] - sim[i][nt][r]);
        ebuf[i * 16 + quad * 4 + r][dbase + nt * 16 + l16] = (bf16_t)e;
        psum[i][r] += e;
      }
#pragma unroll
  for (int m = 1; m < 16; m <<= 1)
#pragma unroll
    for (int i = 0; i < 2; ++i)
#pragma unroll
      for (int r = 0; r < 4; ++r) psum[i][r] += __shfl_xor(psum[i][r], m);
  if (l16 == 0)
#pragma unroll
    for (int i = 0; i < 2; ++i)
#pragma unroll
      for (int r = 0; r < 4; ++r) redsum[wave][i * 16 + quad * 4 + r] = psum[i][r];
  __syncthreads();
  if (tid < 32)
    rowrinv[tid] = 1.f / (redsum[0][tid] + redsum[1][tid] + redsum[2][tid] + redsum[3][tid]);
  __syncthreads();

  // Phase C: out[c][n2] = sum_d e[c][d] * vT[b][n2][d]; wave owns 64 n2-cols x 32 c-rows.
  const bf16_t* vb = vT + (size_t)b * N_ * C_;
  const int n2b = wave * 64;
  f32x4 oacc[2][4];
#pragma unroll
  for (int i = 0; i < 2; ++i)
#pragma unroll
    for (int j = 0; j < 4; ++j) oacc[i][j] = (f32x4){0.f, 0.f, 0.f, 0.f};
  for (int ks = 0; ks < 32; ++ks) {
    const int k0 = ks * 32 + quad * 8;
    bf16x8 ae[2], bf[4];
    ae[0] = *(const bf16x8*)(&ebuf[l16][k0]);
    ae[1] = *(const bf16x8*)(&ebuf[16 + l16][k0]);
#pragma unroll
    for (int j = 0; j < 4; ++j)
      bf[j] = *(const bf16x8*)(vb + (size_t)(n2b + j * 16 + l16) * C_ + k0);
#pragma unroll
    for (int i = 0; i < 2; ++i)
#pragma unroll
      for (int j = 0; j < 4; ++j)
        oacc[i][j] = mfma16(ae[i], bf[j], oacc[i][j]);
  }

  const float alpha = alphap[0];
#pragma unroll
  for (int i = 0; i < 2; ++i)
#pragma unroll
    for (int j = 0; j < 4; ++j)
#pragma unroll
      for (int r = 0; r < 4; ++r) {
        const int c = c0 + i * 16 + quad * 4 + r;
        const int n = n2b + j * 16 + l16;
        const size_t idx = ((size_t)b * C_ + c) * N_ + n;
        out[idx] = alpha * (oacc[i][j][r] * rowrinv[i * 16 + quad * 4 + r]) + x[idx];
      }
}

extern "C" void kernel_launch(void* const* d_in, const int* in_sizes, int n_in,
                              void* d_out, int out_size, void* d_ws, size_t ws_size,
                              hipStream_t stream) {
  const float* x    = (const float*)d_in[0];
  const float* Wq   = (const float*)d_in[1];
  const float* Wk   = (const float*)d_in[2];
  const float* Wv   = (const float*)d_in[3];
  const float* bn1g = (const float*)d_in[4];
  const float* bn1b = (const float*)d_in[5];
  const float* bn1m = (const float*)d_in[6];
  const float* bn1v = (const float*)d_in[7];
  const float* bn2g = (const float*)d_in[8];
  const float* bn2b = (const float*)d_in[9];
  const float* bn2m = (const float*)d_in[10];
  const float* bn2v = (const float*)d_in[11];
  const float* bn3g = (const float*)d_in[12];
  const float* bn3b = (const float*)d_in[13];
  const float* bn3m = (const float*)d_in[14];
  const float* bn3v = (const float*)d_in[15];
  const float* alph = (const float*)d_in[16];
  float* outp = (float*)d_out;

  char* ws = (char*)d_ws;
  bf16_t* qt  = (bf16_t*)(ws);                              // 4 MiB  (B,C,DQ)
  bf16_t* kt  = (bf16_t*)(ws + (size_t)(4u << 20));         // 4 MiB  (B,C,DQ)
  bf16_t* vT  = (bf16_t*)(ws + (size_t)(8u << 20));         // 16 MiB (B,N,C)
  bf16_t* xT  = (bf16_t*)(ws + (size_t)(24u << 20));        // 16 MiB (B,N,C)
  bf16_t* Wvb = (bf16_t*)(ws + (size_t)(40u << 20));        // 2 MiB  (C,C)

  k_trans<<<dim3(8, 32, 32), dim3(32, 8, 1), 0, stream>>>(x, xT);
  k_cvt<<<dim3(512), 256, 0, stream>>>(Wv, Wvb);
  k_qk<<<dim3(4, 32), 256, 0, stream>>>(x, Wq, Wk,
                                        bn1g, bn1b, bn1m, bn1v,
                                        bn2g, bn2b, bn2m, bn2v, qt, kt);
  k_vgemm<<<dim3(8, 2, 32), 256, 0, stream>>>(Wvb, xT, bn3g, bn3b, bn3m, bn3v, vT);
  k_fused<<<dim3(32, 32), 256, 0, stream>>>(qt, kt, vT, x, alph, outp);
}

// Round 4
// 289.281 us; speedup vs baseline: 1.3507x; 1.0266x over previous
//
#include <hip/hip_runtime.h>
#include <hip/hip_bf16.h>

#define B_  32
#define C_  1024
#define N_  256
#define DQ_ 64

typedef __bf16 bf16_t;
typedef __bf16 bf16x8 __attribute__((ext_vector_type(8)));
typedef float  f32x4  __attribute__((ext_vector_type(4)));

static __device__ __forceinline__ f32x4 mfma16(bf16x8 a, bf16x8 b, f32x4 c) {
  return __builtin_amdgcn_mfma_f32_16x16x32_bf16(a, b, c, 0, 0, 0);
}

static __device__ __forceinline__ bf16x8 ldcvt(const float* p) {
  const float4 a = *(const float4*)p;
  const float4 b = *(const float4*)(p + 4);
  bf16x8 r;
  r[0] = (bf16_t)a.x; r[1] = (bf16_t)a.y; r[2] = (bf16_t)a.z; r[3] = (bf16_t)a.w;
  r[4] = (bf16_t)b.x; r[5] = (bf16_t)b.y; r[6] = (bf16_t)b.z; r[7] = (bf16_t)b.w;
  return r;
}

// ---------------- Kernel T: x (B,C,N) f32 -> xT (B,N,C) bf16 ----------------
__global__ __launch_bounds__(256) void k_trans(const float* __restrict__ x,
                                               bf16_t* __restrict__ xT) {
  __shared__ bf16_t tile[32][34];
  const int b  = blockIdx.z;
  const int n0 = blockIdx.x * 32, c0 = blockIdx.y * 32;
  const int tx = threadIdx.x, ty = threadIdx.y;
  const float* xb = x + (size_t)b * C_ * N_;
  bf16_t*     xtb = xT + (size_t)b * N_ * C_;
#pragma unroll
  for (int i = 0; i < 4; ++i)
    tile[ty + i * 8][tx] = (bf16_t)xb[(size_t)(c0 + ty + i * 8) * N_ + (n0 + tx)];
  __syncthreads();
#pragma unroll
  for (int i = 0; i < 4; ++i)
    xtb[(size_t)(n0 + ty + i * 8) * C_ + (c0 + tx)] = tile[tx][ty + i * 8];
}

// ---------------- Kernel CVT: Wv, Wq, Wk f32 -> bf16 ----------------
__global__ __launch_bounds__(256) void k_cvt(const float* __restrict__ Wv,
                                             const float* __restrict__ Wq,
                                             const float* __restrict__ Wk,
                                             bf16_t* __restrict__ Wvb,
                                             bf16_t* __restrict__ Wqkb) {
  const int gid = blockIdx.x * 256 + threadIdx.x;
  if (blockIdx.x < 512) {
    const int i = gid * 8;
    *(bf16x8*)(Wvb + i) = ldcvt(Wv + i);
  } else {
    const int g2 = (gid - 512 * 256) * 8;   // 0 .. 32760
    if (g2 < 16384) *(bf16x8*)(Wqkb + g2) = ldcvt(Wq + g2);
    else            *(bf16x8*)(Wqkb + g2) = ldcvt(Wk + (g2 - 16384));
  }
}

// ---------------- Kernel 1: fused q+k projection ----------------
// Wqkb rows 0..63 = Wq, 64..127 = Wk. Each wave: 16 c-rows x 128 o-rows.
__global__ __launch_bounds__(256) void k_qk(const float* __restrict__ x,
                                            const bf16_t* __restrict__ Wqkb,
                                            const float* __restrict__ g1,
                                            const float* __restrict__ b1,
                                            const float* __restrict__ m1,
                                            const float* __restrict__ v1,
                                            const float* __restrict__ g2,
                                            const float* __restrict__ b2,
                                            const float* __restrict__ m2,
                                            const float* __restrict__ v2,
                                            bf16_t* __restrict__ qt,
                                            bf16_t* __restrict__ kt) {
  const int tid  = threadIdx.x;
  const int wave = tid >> 6;
  const int lane = tid & 63;
  const int quad = lane >> 4;
  const int l16  = lane & 15;
  const int b    = blockIdx.y;
  const int c16  = blockIdx.x * 64 + wave * 16;
  const float* xb = x + (size_t)b * C_ * N_;

  f32x4 acc[8];
#pragma unroll
  for (int i = 0; i < 8; ++i) acc[i] = (f32x4){0.f, 0.f, 0.f, 0.f};

  for (int ks = 0; ks < 8; ++ks) {
    const int k0 = ks * 32 + quad * 8;
    const bf16x8 bx = ldcvt(xb + (size_t)(c16 + l16) * N_ + k0);
#pragma unroll
    for (int i = 0; i < 8; ++i) {
      const bf16x8 aw = *(const bf16x8*)(Wqkb + (size_t)(i * 16 + l16) * N_ + k0);
      acc[i] = mfma16(aw, bx, acc[i]);
    }
  }

#pragma unroll
  for (int i = 0; i < 8; ++i) {
    const bool isq = (i < 4);
    bf16_t* dst = isq ? qt : kt;
#pragma unroll
    for (int r = 0; r < 4; ++r) {
      const int o = (i & 3) * 16 + quad * 4 + r;
      const float sc = (isq ? g1[o] : g2[o]) * rsqrtf((isq ? v1[o] : v2[o]) + 1e-5f);
      const float mm = isq ? m1[o] : m2[o];
      const float bt = isq ? b1[o] : b2[o];
      const int c = c16 + l16;
      float y = (acc[i][r] - mm) * sc + bt;
      y = fmaxf(y, 0.f);
      dst[((size_t)b * C_ + c) * DQ_ + o] = (bf16_t)y;
    }
  }
}

// ---------------- Kernel 2: v GEMM (pure bf16) ----------------
__global__ __launch_bounds__(256) void k_vgemm(const bf16_t* __restrict__ Wvb,
                                               const bf16_t* __restrict__ xT,
                                               const float* __restrict__ g,
                                               const float* __restrict__ be,
                                               const float* __restrict__ mu,
                                               const float* __restrict__ va,
                                               bf16_t* __restrict__ vT) {
  const int tid  = threadIdx.x;
  const int wave = tid >> 6;
  const int lane = tid & 63;
  const int quad = lane >> 4;
  const int l16  = lane & 15;
  const int b    = blockIdx.z;
  const int m0   = blockIdx.x * 128 + (wave >> 1) * 64;
  const int n0   = blockIdx.y * 128 + (wave & 1) * 64;
  const bf16_t* xb = xT + (size_t)b * N_ * C_;

  f32x4 acc[4][4];
#pragma unroll
  for (int i = 0; i < 4; ++i)
#pragma unroll
    for (int j = 0; j < 4; ++j)
      acc[i][j] = (f32x4){0.f, 0.f, 0.f, 0.f};

#pragma unroll 2
  for (int ks = 0; ks < 32; ++ks) {
    const int k0 = ks * 32 + quad * 8;
    bf16x8 a[4], bb[4];
#pragma unroll
    for (int i = 0; i < 4; ++i)
      a[i] = *(const bf16x8*)(Wvb + (size_t)(m0 + i * 16 + l16) * C_ + k0);
#pragma unroll
    for (int j = 0; j < 4; ++j)
      bb[j] = *(const bf16x8*)(xb + (size_t)(n0 + j * 16 + l16) * C_ + k0);
#pragma unroll
    for (int i = 0; i < 4; ++i)
#pragma unroll
      for (int j = 0; j < 4; ++j)
        acc[i][j] = mfma16(a[i], bb[j], acc[i][j]);
  }

#pragma unroll
  for (int i = 0; i < 4; ++i)
#pragma unroll
    for (int r = 0; r < 4; ++r) {
      const int o = m0 + i * 16 + quad * 4 + r;
      const float sc = g[o] * rsqrtf(va[o] + 1e-5f);
      const float mm = mu[o], bt = be[o];
#pragma unroll
      for (int j = 0; j < 4; ++j) {
        const int n = n0 + j * 16 + l16;
        float y = (acc[i][j][r] - mm) * sc + bt;
        y = fmaxf(y, 0.f);
        vT[((size_t)b * N_ + n) * C_ + o] = (bf16_t)y;
      }
    }
}

// ---------------- Kernel 3: fused sim -> softmax -> out ----------------
// 512 threads / 8 waves. Block: 32 c-rows. Phase A: wave owns 128 d-cols.
// Phase C: wave owns 32 n-cols. Register-prefetch software pipeline.
__global__ __launch_bounds__(512, 4) void k_fused(const bf16_t* __restrict__ qt,
                                                  const bf16_t* __restrict__ kt,
                                                  const bf16_t* __restrict__ vT,
                                                  const float* __restrict__ x,
                                                  const float* __restrict__ alphap,
                                                  float* __restrict__ out) {
  __shared__ __align__(16) bf16_t ebuf[32][1032];
  __shared__ float redmin[8][32];
  __shared__ float redsum[8][32];
  __shared__ float rowmin[32];
  __shared__ float rowrinv[32];

  const int tid  = threadIdx.x;
  const int wave = tid >> 6;
  const int lane = tid & 63;
  const int quad = lane >> 4;
  const int l16  = lane & 15;
  const int b    = blockIdx.y;
  const int c0   = blockIdx.x * 32;
  const int dbase = wave * 128;

  // Phase A: sim (32 c-rows x this wave's 128 d-cols, K=64)
  const bf16_t* ktb = kt + ((size_t)b * C_ + c0) * DQ_;
  const bf16_t* qb  = qt + (size_t)b * C_ * DQ_;
  bf16x8 am[2][2];
#pragma unroll
  for (int i = 0; i < 2; ++i) {
    am[i][0] = *(const bf16x8*)(ktb + (size_t)(i * 16 + l16) * DQ_ + quad * 8);
    am[i][1] = *(const bf16x8*)(ktb + (size_t)(i * 16 + l16) * DQ_ + 32 + quad * 8);
  }
  f32x4 sim[2][8];
#pragma unroll
  for (int nt = 0; nt < 8; ++nt) {
    const bf16_t* qrow = qb + (size_t)(dbase + nt * 16 + l16) * DQ_ + quad * 8;
    const bf16x8 b0 = *(const bf16x8*)(qrow);
    const bf16x8 b1 = *(const bf16x8*)(qrow + 32);
#pragma unroll
    for (int i = 0; i < 2; ++i) {
      f32x4 acc = (f32x4){0.f, 0.f, 0.f, 0.f};
      acc = mfma16(am[i][0], b0, acc);
      acc = mfma16(am[i][1], b1, acc);
      sim[i][nt] = acc;
    }
  }

  // Phase B: row-min shift, exp, row-sum.  softmax(M - sim) == exp(min - sim)/S
  float pmin[2][4];
#pragma unroll
  for (int i = 0; i < 2; ++i)
#pragma unroll
    for (int r = 0; r < 4; ++r) pmin[i][r] = sim[i][0][r];
#pragma unroll
  for (int nt = 1; nt < 8; ++nt)
#pragma unroll
    for (int i = 0; i < 2; ++i)
#pragma unroll
      for (int r = 0; r < 4; ++r) pmin[i][r] = fminf(pmin[i][r], sim[i][nt][r]);
#pragma unroll
  for (int m = 1; m < 16; m <<= 1)
#pragma unroll
    for (int i = 0; i < 2; ++i)
#pragma unroll
      for (int r = 0; r < 4; ++r) pmin[i][r] = fminf(pmin[i][r], __shfl_xor(pmin[i][r], m));
  if (l16 == 0)
#pragma unroll
    for (int i = 0; i < 2; ++i)
#pragma unroll
      for (int r = 0; r < 4; ++r) redmin[wave][i * 16 + quad * 4 + r] = pmin[i][r];
  __syncthreads();
  if (tid < 32) {
    float v = redmin[0][tid];
#pragma unroll
    for (int w = 1; w < 8; ++w) v = fminf(v, redmin[w][tid]);
    rowmin[tid] = v;
  }
  __syncthreads();

  float mn[2][4], psum[2][4];
#pragma unroll
  for (int i = 0; i < 2; ++i)
#pragma unroll
    for (int r = 0; r < 4; ++r) {
      mn[i][r] = rowmin[i * 16 + quad * 4 + r];
      psum[i][r] = 0.f;
    }
#pragma unroll
  for (int nt = 0; nt < 8; ++nt)
#pragma unroll
    for (int i = 0; i < 2; ++i)
#pragma unroll
      for (int r = 0; r < 4; ++r) {
        const float e = __expf(mn[i][r] - sim[i][nt][r]);
        ebuf[i * 16 + quad * 4 + r][dbase + nt * 16 + l16] = (bf16_t)e;
        psum[i][r] += e;
      }
#pragma unroll
  for (int m = 1; m < 16; m <<= 1)
#pragma unroll
    for (int i = 0; i < 2; ++i)
#pragma unroll
      for (int r = 0; r < 4; ++r) psum[i][r] += __shfl_xor(psum[i][r], m);
  if (l16 == 0)
#pragma unroll
    for (int i = 0; i < 2; ++i)
#pragma unroll
      for (int r = 0; r < 4; ++r) redsum[wave][i * 16 + quad * 4 + r] = psum[i][r];
  __syncthreads();
  if (tid < 32) {
    float s = redsum[0][tid];
#pragma unroll
    for (int w = 1; w < 8; ++w) s += redsum[w][tid];
    rowrinv[tid] = 1.f / s;
  }
  __syncthreads();

  // Phase C: out[c][n2] = sum_d e[c][d] * vT[b][n2][d]; wave owns 32 n2-cols.
  const bf16_t* vb = vT + (size_t)b * N_ * C_;
  const int n2b = wave * 32;
  f32x4 oacc[2][2];
#pragma unroll
  for (int i = 0; i < 2; ++i)
#pragma unroll
    for (int j = 0; j < 2; ++j) oacc[i][j] = (f32x4){0.f, 0.f, 0.f, 0.f};

  // software pipeline: prefetch next k-step's fragments before current MFMAs
  int k0 = quad * 8;
  bf16x8 ae0 = *(const bf16x8*)(&ebuf[l16][k0]);
  bf16x8 ae1 = *(const bf16x8*)(&ebuf[16 + l16][k0]);
  bf16x8 bv0 = *(const bf16x8*)(vb + (size_t)(n2b + l16) * C_ + k0);
  bf16x8 bv1 = *(const bf16x8*)(vb + (size_t)(n2b + 16 + l16) * C_ + k0);
  for (int ks = 0; ks < 32; ++ks) {
    const int k1 = ((ks + 1) & 31) * 32 + quad * 8;   // wraps on last iter (discarded)
    const bf16x8 ae0n = *(const bf16x8*)(&ebuf[l16][k1]);
    const bf16x8 ae1n = *(const bf16x8*)(&ebuf[16 + l16][k1]);
    const bf16x8 bv0n = *(const bf16x8*)(vb + (size_t)(n2b + l16) * C_ + k1);
    const bf16x8 bv1n = *(const bf16x8*)(vb + (size_t)(n2b + 16 + l16) * C_ + k1);
    oacc[0][0] = mfma16(ae0, bv0, oacc[0][0]);
    oacc[0][1] = mfma16(ae0, bv1, oacc[0][1]);
    oacc[1][0] = mfma16(ae1, bv0, oacc[1][0]);
    oacc[1][1] = mfma16(ae1, bv1, oacc[1][1]);
    ae0 = ae0n; ae1 = ae1n; bv0 = bv0n; bv1 = bv1n;
  }

  const float alpha = alphap[0];
#pragma unroll
  for (int i = 0; i < 2; ++i)
#pragma unroll
    for (int j = 0; j < 2; ++j)
#pragma unroll
      for (int r = 0; r < 4; ++r) {
        const int c = c0 + i * 16 + quad * 4 + r;
        const int n = n2b + j * 16 + l16;
        const size_t idx = ((size_t)b * C_ + c) * N_ + n;
        out[idx] = alpha * (oacc[i][j][r] * rowrinv[i * 16 + quad * 4 + r]) + x[idx];
      }
}

extern "C" void kernel_launch(void* const* d_in, const int* in_sizes, int n_in,
                              void* d_out, int out_size, void* d_ws, size_t ws_size,
                              hipStream_t stream) {
  const float* x    = (const float*)d_in[0];
  const float* Wq   = (const float*)d_in[1];
  const float* Wk   = (const float*)d_in[2];
  const float* Wv   = (const float*)d_in[3];
  const float* bn1g = (const float*)d_in[4];
  const float* bn1b = (const float*)d_in[5];
  const float* bn1m = (const float*)d_in[6];
  const float* bn1v = (const float*)d_in[7];
  const float* bn2g = (const float*)d_in[8];
  const float* bn2b = (const float*)d_in[9];
  const float* bn2m = (const float*)d_in[10];
  const float* bn2v = (const float*)d_in[11];
  const float* bn3g = (const float*)d_in[12];
  const float* bn3b = (const float*)d_in[13];
  const float* bn3m = (const float*)d_in[14];
  const float* bn3v = (const float*)d_in[15];
  const float* alph = (const float*)d_in[16];
  float* outp = (float*)d_out;

  char* ws = (char*)d_ws;
  bf16_t* qt   = (bf16_t*)(ws);                              // 4 MiB  (B,C,DQ)
  bf16_t* kt   = (bf16_t*)(ws + (size_t)(4u << 20));         // 4 MiB  (B,C,DQ)
  bf16_t* vT   = (bf16_t*)(ws + (size_t)(8u << 20));         // 16 MiB (B,N,C)
  bf16_t* xT   = (bf16_t*)(ws + (size_t)(24u << 20));        // 16 MiB (B,N,C)
  bf16_t* Wvb  = (bf16_t*)(ws + (size_t)(40u << 20));        // 2 MiB  (C,C)
  bf16_t* Wqkb = (bf16_t*)(ws + (size_t)(42u << 20));        // 64 KiB (128,N)

  k_trans<<<dim3(8, 32, 32), dim3(32, 8, 1), 0, stream>>>(x, xT);
  k_cvt<<<dim3(528), 256, 0, stream>>>(Wv, Wq, Wk, Wvb, Wqkb);
  k_qk<<<dim3(16, 32), 256, 0, stream>>>(x, Wqkb,
                                         bn1g, bn1b, bn1m, bn1v,
                                         bn2g, bn2b, bn2m, bn2v, qt, kt);
  k_vgemm<<<dim3(8, 2, 32), 256, 0, stream>>>(Wvb, xT, bn3g, bn3b, bn3m, bn3v, vT);
  k_fused<<<dim3(32, 32), 512, 0, stream>>>(qt, kt, vT, x, alph, outp);
}

// Round 5
// 251.018 us; speedup vs baseline: 1.5566x; 1.1524x over previous
//
#include <hip/hip_runtime.h>
#include <hip/hip_bf16.h>

#define B_  32
#define C_  1024
#define N_  256
#define DQ_ 64

typedef __bf16 bf16_t;
typedef __bf16 bf16x8 __attribute__((ext_vector_type(8)));
typedef float  f32x4  __attribute__((ext_vector_type(4)));

static __device__ __forceinline__ f32x4 mfma16(bf16x8 a, bf16x8 b, f32x4 c) {
  return __builtin_amdgcn_mfma_f32_16x16x32_bf16(a, b, c, 0, 0, 0);
}

static __device__ __forceinline__ bf16x8 ldcvt(const float* p) {
  const float4 a = *(const float4*)p;
  const float4 b = *(const float4*)(p + 4);
  bf16x8 r;
  r[0] = (bf16_t)a.x; r[1] = (bf16_t)a.y; r[2] = (bf16_t)a.z; r[3] = (bf16_t)a.w;
  r[4] = (bf16_t)b.x; r[5] = (bf16_t)b.y; r[6] = (bf16_t)b.z; r[7] = (bf16_t)b.w;
  return r;
}

// Swizzled global->LDS staging: each wave stages 32 rows of 64 bf16 (128 B) via
// 4 x global_load_lds(16B). Row r, slot j (16B chunks) holds global chunk
// (j - r) & 7, so frag ds_read_b128 across l16 lands 2 lanes/bank-group (free).
static __device__ __forceinline__ void stage32(const bf16_t* grow0, size_t gstride,
                                               bf16_t* tile, int wave, int lane) {
#pragma unroll
  for (int t = 0; t < 4; ++t) {
    const int rb = wave * 32 + t * 8;
    const int r  = rb + (lane >> 3);
    const int g  = ((lane & 7) - r) & 7;
    const bf16_t* src = grow0 + (size_t)r * gstride + g * 8;
    __builtin_amdgcn_global_load_lds(
        (const __attribute__((address_space(1))) void*)src,
        (__attribute__((address_space(3))) void*)(tile + rb * 64), 16, 0, 0);
  }
}

// ---------------- Kernel T: x (B,C,N) f32 -> xT (B,N,C) bf16 ----------------
__global__ __launch_bounds__(256) void k_trans(const float* __restrict__ x,
                                               bf16_t* __restrict__ xT) {
  __shared__ bf16_t tile[32][34];
  const int b  = blockIdx.z;
  const int n0 = blockIdx.x * 32, c0 = blockIdx.y * 32;
  const int tx = threadIdx.x, ty = threadIdx.y;
  const float* xb = x + (size_t)b * C_ * N_;
  bf16_t*     xtb = xT + (size_t)b * N_ * C_;
#pragma unroll
  for (int i = 0; i < 4; ++i)
    tile[ty + i * 8][tx] = (bf16_t)xb[(size_t)(c0 + ty + i * 8) * N_ + (n0 + tx)];
  __syncthreads();
#pragma unroll
  for (int i = 0; i < 4; ++i)
    xtb[(size_t)(n0 + ty + i * 8) * C_ + (c0 + tx)] = tile[tx][ty + i * 8];
}

// ---------------- Kernel CVT: Wv, Wq, Wk f32 -> bf16 ----------------
__global__ __launch_bounds__(256) void k_cvt(const float* __restrict__ Wv,
                                             const float* __restrict__ Wq,
                                             const float* __restrict__ Wk,
                                             bf16_t* __restrict__ Wvb,
                                             bf16_t* __restrict__ Wqkb) {
  const int gid = blockIdx.x * 256 + threadIdx.x;
  if (blockIdx.x < 512) {
    const int i = gid * 8;
    *(bf16x8*)(Wvb + i) = ldcvt(Wv + i);
  } else {
    const int g2 = (gid - 512 * 256) * 8;
    if (g2 < 16384) *(bf16x8*)(Wqkb + g2) = ldcvt(Wq + g2);
    else            *(bf16x8*)(Wqkb + g2) = ldcvt(Wk + (g2 - 16384));
  }
}

// ---------------- Kernel 1: fused q+k projection ----------------
__global__ __launch_bounds__(256) void k_qk(const float* __restrict__ x,
                                            const bf16_t* __restrict__ Wqkb,
                                            const float* __restrict__ g1,
                                            const float* __restrict__ b1,
                                            const float* __restrict__ m1,
                                            const float* __restrict__ v1,
                                            const float* __restrict__ g2,
                                            const float* __restrict__ b2,
                                            const float* __restrict__ m2,
                                            const float* __restrict__ v2,
                                            bf16_t* __restrict__ qt,
                                            bf16_t* __restrict__ kt) {
  const int tid  = threadIdx.x;
  const int wave = tid >> 6;
  const int lane = tid & 63;
  const int quad = lane >> 4;
  const int l16  = lane & 15;
  const int b    = blockIdx.y;
  const int c16  = blockIdx.x * 64 + wave * 16;
  const float* xb = x + (size_t)b * C_ * N_;

  f32x4 acc[8];
#pragma unroll
  for (int i = 0; i < 8; ++i) acc[i] = (f32x4){0.f, 0.f, 0.f, 0.f};

  for (int ks = 0; ks < 8; ++ks) {
    const int k0 = ks * 32 + quad * 8;
    const bf16x8 bx = ldcvt(xb + (size_t)(c16 + l16) * N_ + k0);
#pragma unroll
    for (int i = 0; i < 8; ++i) {
      const bf16x8 aw = *(const bf16x8*)(Wqkb + (size_t)(i * 16 + l16) * N_ + k0);
      acc[i] = mfma16(aw, bx, acc[i]);
    }
  }

#pragma unroll
  for (int i = 0; i < 8; ++i) {
    const bool isq = (i < 4);
    bf16_t* dst = isq ? qt : kt;
#pragma unroll
    for (int r = 0; r < 4; ++r) {
      const int o = (i & 3) * 16 + quad * 4 + r;
      const float sc = (isq ? g1[o] : g2[o]) * rsqrtf((isq ? v1[o] : v2[o]) + 1e-5f);
      const float mm = isq ? m1[o] : m2[o];
      const float bt = isq ? b1[o] : b2[o];
      const int c = c16 + l16;
      float y = (acc[i][r] - mm) * sc + bt;
      y = fmaxf(y, 0.f);
      dst[((size_t)b * C_ + c) * DQ_ + o] = (bf16_t)y;
    }
  }
}

// ---------------- Kernel 2: v GEMM, m97-style staged (flat 8192x1024x1024) ----
__global__ __launch_bounds__(256, 2) void k_vgemm(const bf16_t* __restrict__ Wvb,
                                                  const bf16_t* __restrict__ xT,
                                                  const float* __restrict__ g,
                                                  const float* __restrict__ be,
                                                  const float* __restrict__ mu,
                                                  const float* __restrict__ va,
                                                  bf16_t* __restrict__ vT) {
  __shared__ __align__(16) bf16_t As[2][128 * 64];
  __shared__ __align__(16) bf16_t Bs[2][128 * 64];
  const int tid  = threadIdx.x;
  const int wave = tid >> 6;
  const int lane = tid & 63;
  const int quad = lane >> 4;
  const int l16  = lane & 15;
  const int o0 = blockIdx.x * 128;
  const int r0 = blockIdx.y * 128;   // flat row = b*N_ + n
  const bf16_t* Ab = Wvb + (size_t)o0 * C_;
  const bf16_t* Bb = xT + (size_t)r0 * C_;
  const int wr = (wave >> 1) * 64, wc = (wave & 1) * 64;

  stage32(Ab, C_, (bf16_t*)As[0], wave, lane);
  stage32(Bb, C_, (bf16_t*)Bs[0], wave, lane);

  f32x4 acc[4][4];
#pragma unroll
  for (int i = 0; i < 4; ++i)
#pragma unroll
    for (int j = 0; j < 4; ++j) acc[i][j] = (f32x4){0.f, 0.f, 0.f, 0.f};

  for (int ks = 0; ks < 16; ++ks) {
    __syncthreads();
    const bf16_t* ca = As[ks & 1];
    const bf16_t* cb = Bs[ks & 1];
    if (ks < 15) {
      stage32(Ab + (ks + 1) * 64, C_, (bf16_t*)As[(ks + 1) & 1], wave, lane);
      stage32(Bb + (ks + 1) * 64, C_, (bf16_t*)Bs[(ks + 1) & 1], wave, lane);
    }
#pragma unroll
    for (int ksub = 0; ksub < 2; ++ksub) {
      bf16x8 a[4], bfr[4];
#pragma unroll
      for (int i = 0; i < 4; ++i) {
        const int r = wr + i * 16 + l16;
        const int s = ((ksub * 4 + quad) + r) & 7;
        a[i] = *(const bf16x8*)(ca + r * 64 + s * 8);
      }
#pragma unroll
      for (int j = 0; j < 4; ++j) {
        const int r = wc + j * 16 + l16;
        const int s = ((ksub * 4 + quad) + r) & 7;
        bfr[j] = *(const bf16x8*)(cb + r * 64 + s * 8);
      }
#pragma unroll
      for (int i = 0; i < 4; ++i)
#pragma unroll
        for (int j = 0; j < 4; ++j)
          acc[i][j] = mfma16(a[i], bfr[j], acc[i][j]);
    }
  }

#pragma unroll
  for (int i = 0; i < 4; ++i)
#pragma unroll
    for (int r = 0; r < 4; ++r) {
      const int o = o0 + wr + i * 16 + quad * 4 + r;
      const float sc = g[o] * rsqrtf(va[o] + 1e-5f);
      const float mm = mu[o], bt = be[o];
#pragma unroll
      for (int j = 0; j < 4; ++j) {
        const int rG = r0 + wc + j * 16 + l16;
        float y = (acc[i][j][r] - mm) * sc + bt;
        y = fmaxf(y, 0.f);
        vT[(size_t)rG * C_ + o] = (bf16_t)y;
      }
    }
}

// ---------------- Kernel 3: fused sim -> softmax -> out (staged) ----------------
// 512 thr / 8 waves. Block: one (b, 32 c-rows) tile; XCD-swizzled 1-D grid.
// ebuf: 32x1024 bf16, chunk-rotated (slot = (chunk + c) & 7 within 8-chunk groups).
static __device__ __forceinline__ int eaddr(int c, int d) {
  const int ch = d >> 3;
  const int ph = (ch & ~7) | ((ch + c) & 7);
  return (c << 10) + (ph << 3) + (d & 7);
}

__global__ __launch_bounds__(512, 2) void k_fused(const bf16_t* __restrict__ qt,
                                                  const bf16_t* __restrict__ kt,
                                                  const bf16_t* __restrict__ vT,
                                                  const float* __restrict__ x,
                                                  const float* __restrict__ alphap,
                                                  float* __restrict__ out) {
  __shared__ __align__(16) bf16_t ebuf[32 * 1024];
  __shared__ __align__(16) bf16_t vs[2][256 * 64];
  __shared__ float redmin[8][32];
  __shared__ float redsum[8][32];
  __shared__ float rowmin[32];
  __shared__ float rowrinv[32];

  const int tid  = threadIdx.x;
  const int wave = tid >> 6;
  const int lane = tid & 63;
  const int quad = lane >> 4;
  const int l16  = lane & 15;
  const int id   = blockIdx.x;
  const int b    = ((id & 7) << 2) | (id >> 8);        // 32 blocks/batch on one XCD
  const int c0   = ((id >> 3) & 31) << 5;

  const bf16_t* qb  = qt + (size_t)b * C_ * DQ_;
  const bf16_t* ktb = kt + ((size_t)b * C_ + c0) * DQ_;

  bf16x8 am[2][2];
#pragma unroll
  for (int i = 0; i < 2; ++i)
#pragma unroll
    for (int ksub = 0; ksub < 2; ++ksub)
      am[i][ksub] = *(const bf16x8*)(ktb + (size_t)(i * 16 + l16) * DQ_ + ksub * 32 + quad * 8);

  // ---- Phase A: sim (32 c x 1024 d), qt staged in 4 x 256-row tiles ----
  stage32(qb, DQ_, (bf16_t*)vs[0], wave, lane);
  f32x4 sim[2][8];
#pragma unroll
  for (int i = 0; i < 2; ++i)
#pragma unroll
    for (int nt = 0; nt < 8; ++nt) sim[i][nt] = (f32x4){0.f, 0.f, 0.f, 0.f};

  for (int t = 0; t < 4; ++t) {
    __syncthreads();
    const bf16_t* cur = vs[t & 1];
    if (t < 3) stage32(qb + (size_t)(t + 1) * 256 * DQ_, DQ_, (bf16_t*)vs[(t + 1) & 1], wave, lane);
#pragma unroll
    for (int jn = 0; jn < 2; ++jn) {
      const int r = wave * 32 + jn * 16 + l16;
#pragma unroll
      for (int ksub = 0; ksub < 2; ++ksub) {
        const int s = ((ksub * 4 + quad) + r) & 7;
        const bf16x8 bq = *(const bf16x8*)(cur + r * 64 + s * 8);
        sim[0][t * 2 + jn] = mfma16(am[0][ksub], bq, sim[0][t * 2 + jn]);
        sim[1][t * 2 + jn] = mfma16(am[1][ksub], bq, sim[1][t * 2 + jn]);
      }
    }
  }

  // Prologue staging for Phase C (overlaps Phase B work)
  const bf16_t* vb = vT + (size_t)b * N_ * C_;
  stage32(vb, C_, (bf16_t*)vs[0], wave, lane);

  // ---- Phase B: row-min shift, exp, row-sum ----
  float pmin[2][4];
#pragma unroll
  for (int i = 0; i < 2; ++i)
#pragma unroll
    for (int r = 0; r < 4; ++r) pmin[i][r] = sim[i][0][r];
#pragma unroll
  for (int nt = 1; nt < 8; ++nt)
#pragma unroll
    for (int i = 0; i < 2; ++i)
#pragma unroll
      for (int r = 0; r < 4; ++r) pmin[i][r] = fminf(pmin[i][r], sim[i][nt][r]);
#pragma unroll
  for (int m = 1; m < 16; m <<= 1)
#pragma unroll
    for (int i = 0; i < 2; ++i)
#pragma unroll
      for (int r = 0; r < 4; ++r) pmin[i][r] = fminf(pmin[i][r], __shfl_xor(pmin[i][r], m));
  if (l16 == 0)
#pragma unroll
    for (int i = 0; i < 2; ++i)
#pragma unroll
      for (int r = 0; r < 4; ++r) redmin[wave][i * 16 + quad * 4 + r] = pmin[i][r];
  __syncthreads();
  if (tid < 32) {
    float v = redmin[0][tid];
#pragma unroll
    for (int w = 1; w < 8; ++w) v = fminf(v, redmin[w][tid]);
    rowmin[tid] = v;
  }
  __syncthreads();

  float mn[2][4], psum[2][4];
#pragma unroll
  for (int i = 0; i < 2; ++i)
#pragma unroll
    for (int r = 0; r < 4; ++r) {
      mn[i][r] = rowmin[i * 16 + quad * 4 + r];
      psum[i][r] = 0.f;
    }
#pragma unroll
  for (int nt = 0; nt < 8; ++nt) {
    const int d = ((nt >> 1) << 8) + wave * 32 + ((nt & 1) << 4) + l16;
#pragma unroll
    for (int i = 0; i < 2; ++i)
#pragma unroll
      for (int r = 0; r < 4; ++r) {
        const int c = i * 16 + quad * 4 + r;
        const float e = __expf(mn[i][r] - sim[i][nt][r]);
        ebuf[eaddr(c, d)] = (bf16_t)e;
        psum[i][r] += e;
      }
  }
#pragma unroll
  for (int m = 1; m < 16; m <<= 1)
#pragma unroll
    for (int i = 0; i < 2; ++i)
#pragma unroll
      for (int r = 0; r < 4; ++r) psum[i][r] += __shfl_xor(psum[i][r], m);
  if (l16 == 0)
#pragma unroll
    for (int i = 0; i < 2; ++i)
#pragma unroll
      for (int r = 0; r < 4; ++r) redsum[wave][i * 16 + quad * 4 + r] = psum[i][r];
  __syncthreads();
  if (tid < 32) {
    float s = redsum[0][tid];
#pragma unroll
    for (int w = 1; w < 8; ++w) s += redsum[w][tid];
    rowrinv[tid] = 1.f / s;
  }

  // ---- Phase C: out = e @ vT, vT staged in 16 x (256 n x 64 d) tiles ----
  f32x4 oacc[2][2];
#pragma unroll
  for (int i = 0; i < 2; ++i)
#pragma unroll
    for (int jn = 0; jn < 2; ++jn) oacc[i][jn] = (f32x4){0.f, 0.f, 0.f, 0.f};

  for (int ks = 0; ks < 16; ++ks) {
    __syncthreads();
    const bf16_t* cur = vs[ks & 1];
    if (ks < 15) stage32(vb + (ks + 1) * 64, C_, (bf16_t*)vs[(ks + 1) & 1], wave, lane);
#pragma unroll
    for (int ksub = 0; ksub < 2; ++ksub) {
      const int gch = ks * 8 + ksub * 4 + quad;
      const int ph  = (gch & ~7) | ((gch + l16) & 7);
      const bf16x8 ae0 = *(const bf16x8*)(ebuf + ((size_t)l16 << 10) + ph * 8);
      const bf16x8 ae1 = *(const bf16x8*)(ebuf + ((size_t)(16 + l16) << 10) + ph * 8);
#pragma unroll
      for (int jn = 0; jn < 2; ++jn) {
        const int r = wave * 32 + jn * 16 + l16;
        const int s = ((ksub * 4 + quad) + r) & 7;
        const bf16x8 bv = *(const bf16x8*)(cur + r * 64 + s * 8);
        oacc[0][jn] = mfma16(ae0, bv, oacc[0][jn]);
        oacc[1][jn] = mfma16(ae1, bv, oacc[1][jn]);
      }
    }
  }

  const float alpha = alphap[0];
#pragma unroll
  for (int i = 0; i < 2; ++i)
#pragma unroll
    for (int jn = 0; jn < 2; ++jn)
#pragma unroll
      for (int r = 0; r < 4; ++r) {
        const int c = c0 + i * 16 + quad * 4 + r;
        const int n = wave * 32 + jn * 16 + l16;
        const size_t idx = ((size_t)b * C_ + c) * N_ + n;
        out[idx] = alpha * (oacc[i][jn][r] * rowrinv[i * 16 + quad * 4 + r]) + x[idx];
      }
}

extern "C" void kernel_launch(void* const* d_in, const int* in_sizes, int n_in,
                              void* d_out, int out_size, void* d_ws, size_t ws_size,
                              hipStream_t stream) {
  const float* x    = (const float*)d_in[0];
  const float* Wq   = (const float*)d_in[1];
  const float* Wk   = (const float*)d_in[2];
  const float* Wv   = (const float*)d_in[3];
  const float* bn1g = (const float*)d_in[4];
  const float* bn1b = (const float*)d_in[5];
  const float* bn1m = (const float*)d_in[6];
  const float* bn1v = (const float*)d_in[7];
  const float* bn2g = (const float*)d_in[8];
  const float* bn2b = (const float*)d_in[9];
  const float* bn2m = (const float*)d_in[10];
  const float* bn2v = (const float*)d_in[11];
  const float* bn3g = (const float*)d_in[12];
  const float* bn3b = (const float*)d_in[13];
  const float* bn3m = (const float*)d_in[14];
  const float* bn3v = (const float*)d_in[15];
  const float* alph = (const float*)d_in[16];
  float* outp = (float*)d_out;

  char* ws = (char*)d_ws;
  bf16_t* qt   = (bf16_t*)(ws);                              // 4 MiB  (B,C,DQ)
  bf16_t* kt   = (bf16_t*)(ws + (size_t)(4u << 20));         // 4 MiB  (B,C,DQ)
  bf16_t* vT   = (bf16_t*)(ws + (size_t)(8u << 20));         // 16 MiB (B,N,C)
  bf16_t* xT   = (bf16_t*)(ws + (size_t)(24u << 20));        // 16 MiB (B,N,C)
  bf16_t* Wvb  = (bf16_t*)(ws + (size_t)(40u << 20));        // 2 MiB  (C,C)
  bf16_t* Wqkb = (bf16_t*)(ws + (size_t)(42u << 20));        // 64 KiB (128,N)

  k_trans<<<dim3(8, 32, 32), dim3(32, 8, 1), 0, stream>>>(x, xT);
  k_cvt<<<dim3(528), 256, 0, stream>>>(Wv, Wq, Wk, Wvb, Wqkb);
  k_qk<<<dim3(16, 32), 256, 0, stream>>>(x, Wqkb,
                                         bn1g, bn1b, bn1m, bn1v,
                                         bn2g, bn2b, bn2m, bn2v, qt, kt);
  k_vgemm<<<dim3(8, 64), 256, 0, stream>>>(Wvb, xT, bn3g, bn3b, bn3m, bn3v, vT);
  k_fused<<<dim3(1024), 512, 0, stream>>>(qt, kt, vT, x, alph, outp);
}